// Round 7
// baseline (282.500 us; speedup 1.0000x reference)
//
#include <hip/hip_runtime.h>
#include <hip/hip_bf16.h>

#define ALPHA 0.2f
typedef unsigned int uint32;
typedef __attribute__((ext_vector_type(8))) short short8;   // 8 bf16 = 4 VGPRs
typedef __attribute__((ext_vector_type(4))) float f32x4;    // native 4xf32 (NT-capable)
typedef __attribute__((ext_vector_type(2))) float f32x2;    // native 2xf32

static __device__ __forceinline__ unsigned short f2bf(float f) {
    unsigned int u = __float_as_uint(f);
    u += 0x7fffu + ((u >> 16) & 1u);          // RNE
    return (unsigned short)(u >> 16);
}
static __device__ __forceinline__ uint32 pk2bf(float lo, float hi) {
    return (uint32)f2bf(lo) | ((uint32)f2bf(hi) << 16);
}
static __device__ __forceinline__ float bflo(uint32 u) { return __uint_as_float(u << 16); }
static __device__ __forceinline__ float bfhi(uint32 u) { return __uint_as_float(u & 0xffff0000u); }

// ---------------------------------------------------------------------------
// prep2: fold W into everything downstream (associativity: Y_k = h@(W@Wout_k),
// s1 = h@(W@a1)).  Blocks 0..23: WT2[s][n][j] = bf16( sum_c W[j][c] *
// Wout[s*128+c][n] )  (B^T layout for MFMA).  Block 24: w1f[j]=sum_c W[j][c]
// a1[c], w2f likewise (fp32).  W staged transposed in LDS (pad 129).
// ---------------------------------------------------------------------------
__global__ __launch_bounds__(256) void prep2_kernel(const float* __restrict__ W,
                                                    const float* __restrict__ Wout,
                                                    const float* __restrict__ a1,
                                                    const float* __restrict__ a2,
                                                    unsigned short* __restrict__ WT2,
                                                    float* __restrict__ w1f,
                                                    float* __restrict__ w2f) {
    __shared__ float WT_lds[129 * 128];   // [c][j] = W[j][c], pad 129 (~66KB)
    __shared__ float Wos[128 * 16];       // [c][q] Wout slice cols
    const int tid = threadIdx.x;
    for (int i = tid; i < 16384; i += 256) {
        int j = i >> 7, c = i & 127;
        WT_lds[c * 129 + j] = W[i];
    }
    if (blockIdx.x < 24) {
        int s = blockIdx.x >> 3, nb = blockIdx.x & 7;
        for (int i = tid; i < 2048; i += 256) {
            int c = i >> 4, q = i & 15;
            Wos[i] = Wout[(size_t)(s * 128 + c) * 128 + nb * 16 + q];
        }
        __syncthreads();
        int j = tid & 127, nh = tid >> 7;
        float acc[8];
#pragma unroll
        for (int p = 0; p < 8; ++p) acc[p] = 0.f;
        for (int c = 0; c < 128; ++c) {
            float w = WT_lds[c * 129 + j];
#pragma unroll
            for (int p = 0; p < 8; ++p) acc[p] += w * Wos[c * 16 + nh * 8 + p];
        }
#pragma unroll
        for (int p = 0; p < 8; ++p) {
            int n = nb * 16 + nh * 8 + p;
            WT2[((size_t)s * 128 + n) * 128 + j] = f2bf(acc[p]);
        }
    } else {
        __syncthreads();
        if (tid < 128) {
            float acc1 = 0.f, acc2 = 0.f;
            for (int c = 0; c < 128; ++c) {
                float w = WT_lds[c * 129 + tid];
                acc1 += w * a1[c];
                acc2 += w * a2[c];
            }
            w1f[tid] = acc1;
            w2f[tid] = acc2;
        }
    }
}

// ---------------------------------------------------------------------------
// mmy2: Yb[M,384] = bf16(h) @ M_k (all 3 slices per block) via 16x16x32 bf16
// MFMA.  h loads NT (read-once stream).  Yb stores NT: lines land clean in
// L3 instead of dirty in this XCD's L2 -> agg's cross-XCD random reads avoid
// dirty-probe services.  s1/s2 fused fp32 in the staging pass.
// ---------------------------------------------------------------------------
__global__ __launch_bounds__(256) void mmy2_kernel(const float* __restrict__ h,
                                                   const unsigned short* __restrict__ WT2,
                                                   const float* __restrict__ w1f,
                                                   const float* __restrict__ w2f,
                                                   unsigned short* __restrict__ Yb,
                                                   float* __restrict__ s1,
                                                   float* __restrict__ s2, int M) {
    __shared__ unsigned short As[128 * 128];
    __shared__ unsigned short Bs[128 * 128];
    __shared__ float ws1[128], ws2[128];
    const int tid  = threadIdx.x;
    const int lane = tid & 63;
    const int w    = tid >> 6;
    const int row0 = blockIdx.x * 128;

    if (tid < 128) ws1[tid] = w1f[tid];
    else           ws2[tid - 128] = w2f[tid - 128];
    __syncthreads();

    // ---- stage A (fp32 -> bf16) + fused fp32 score partials ----
    const f32x4* h4 = (const f32x4*)h;
    float sp1[8], sp2[8];
#pragma unroll
    for (int m = 0; m < 8; ++m) { sp1[m] = 0.f; sp2[m] = 0.f; }
#pragma unroll
    for (int m = 0; m < 8; ++m) {
        int i = m * 256 + tid;            // 0..2047
        int r = i >> 4, g = i & 15;
        int rg = row0 + r;
        f32x4 va = (f32x4){0.f, 0.f, 0.f, 0.f}, vb = va;
        if (rg < M) {
            va = __builtin_nontemporal_load(h4 + (size_t)rg * 32 + g * 2);
            vb = __builtin_nontemporal_load(h4 + (size_t)rg * 32 + g * 2 + 1);
        }
        float4 wa1 = *(const float4*)(ws1 + g * 8);
        float4 wb1 = *(const float4*)(ws1 + g * 8 + 4);
        float4 wa2 = *(const float4*)(ws2 + g * 8);
        float4 wb2 = *(const float4*)(ws2 + g * 8 + 4);
        sp1[m] += va.x * wa1.x + va.y * wa1.y + va.z * wa1.z + va.w * wa1.w
                + vb.x * wb1.x + vb.y * wb1.y + vb.z * wb1.z + vb.w * wb1.w;
        sp2[m] += va.x * wa2.x + va.y * wa2.y + va.z * wa2.z + va.w * wa2.w
                + vb.x * wb2.x + vb.y * wb2.y + vb.z * wb2.z + vb.w * wb2.w;
        uint4 u;
        u.x = pk2bf(va.x, va.y); u.y = pk2bf(va.z, va.w);
        u.z = pk2bf(vb.x, vb.y); u.w = pk2bf(vb.z, vb.w);
        *(uint4*)(As + r * 128 + ((g ^ (r & 15)) * 8)) = u;
    }
    // reduce scores across the 16 threads sharing each row
#pragma unroll
    for (int m = 0; m < 8; ++m) {
#pragma unroll
        for (int off = 1; off < 16; off <<= 1) {
            sp1[m] += __shfl_xor(sp1[m], off);
            sp2[m] += __shfl_xor(sp2[m], off);
        }
    }
    if ((tid & 15) == 0) {
#pragma unroll
        for (int m = 0; m < 8; ++m) {
            int rg = row0 + m * 16 + (tid >> 4);
            if (rg < M) { s1[rg] = sp1[m]; s2[rg] = sp2[m]; }
        }
    }

    const int ml   = lane & 15;
    const int quad = lane >> 4;
    for (int ks = 0; ks < 3; ++ks) {
        __syncthreads();                          // prev compute done / As ready
#pragma unroll
        for (int m = 0; m < 8; ++m) {             // stage Bs = WT2[ks]
            int i = m * 256 + tid;
            int n = i >> 4, g = i & 15;
            uint4 v = *(const uint4*)(WT2 + (size_t)ks * 16384 + n * 128 + g * 8);
            *(uint4*)(Bs + n * 128 + ((g ^ (n & 15)) * 8)) = v;
        }
        __syncthreads();

        f32x4 acc[2][8];
#pragma unroll
        for (int mt = 0; mt < 2; ++mt)
#pragma unroll
            for (int nt = 0; nt < 8; ++nt) acc[mt][nt] = (f32x4){0.f, 0.f, 0.f, 0.f};
#pragma unroll
        for (int kc = 0; kc < 4; ++kc) {
            int gl = ((kc * 4 + quad) ^ ml) * 8;
            short8 af0 = *(const short8*)(As + (w * 32 + ml) * 128 + gl);
            short8 af1 = *(const short8*)(As + (w * 32 + 16 + ml) * 128 + gl);
#pragma unroll
            for (int nt = 0; nt < 8; ++nt) {
                short8 bf = *(const short8*)(Bs + (nt * 16 + ml) * 128 + gl);
                acc[0][nt] = __builtin_amdgcn_mfma_f32_16x16x32_bf16(af0, bf, acc[0][nt], 0, 0, 0);
                acc[1][nt] = __builtin_amdgcn_mfma_f32_16x16x32_bf16(af1, bf, acc[1][nt], 0, 0, 0);
            }
        }
#pragma unroll
        for (int mt = 0; mt < 2; ++mt) {
            int rbase = row0 + w * 32 + mt * 16 + quad * 4;
#pragma unroll
            for (int r = 0; r < 4; ++r) {
                int rg = rbase + r;
                if (rg >= M) continue;
                unsigned short* yrow = Yb + (size_t)rg * 384 + ks * 128 + ml;
#pragma unroll
                for (int nt = 0; nt < 8; ++nt)
                    __builtin_nontemporal_store(f2bf(acc[mt][nt][r]), yrow + nt * 16);
            }
        }
    }
}

// ---------------------------------------------------------------------------
// hist: counts[dst]++ per edge AND record slot-within-node. Streams NT.
// ---------------------------------------------------------------------------
__global__ __launch_bounds__(256) void hist_kernel(const int* __restrict__ ei,
                                                   int* __restrict__ counts,
                                                   int* __restrict__ eslot, int E) {
    int e = blockIdx.x * blockDim.x + threadIdx.x;
    if (e < E) {
        int d = __builtin_nontemporal_load(ei + E + e);
        int slot = atomicAdd(&counts[d], 1);
        __builtin_nontemporal_store(slot, eslot + e);
    }
}

// ---------------------------------------------------------------------------
// scan_fused: rowptr from counts in ONE kernel. Each of the ~49 blocks first
// re-reduces counts[0 .. blk*1024) from L2 (~5 MB total L2 traffic across the
// grid) to get its global base, then scans its own 1024-chunk.
// ---------------------------------------------------------------------------
__global__ __launch_bounds__(256) void scan_fused_kernel(const int* __restrict__ counts,
                                                         int* __restrict__ rowptr,
                                                         int N, int E) {
    __shared__ int wsums[4];
    __shared__ int base_s;
    const int tid = threadIdx.x, lane = tid & 63, wv = tid >> 6;

    // phase 1: base = sum of counts before this chunk (limit is mult. of 1024)
    const int limit = blockIdx.x * 1024;
    int acc = 0;
    for (int i = tid * 4; i < limit; i += 1024) {
        int4 v = *(const int4*)(counts + i);
        acc += v.x + v.y + v.z + v.w;
    }
#pragma unroll
    for (int off = 32; off > 0; off >>= 1) acc += __shfl_down(acc, off);
    if (lane == 0) wsums[wv] = acc;
    __syncthreads();
    if (tid == 0) base_s = wsums[0] + wsums[1] + wsums[2] + wsums[3];
    __syncthreads();

    // phase 2: scan own chunk
    int i0 = blockIdx.x * 1024 + tid * 4;
    int v0 = 0, v1 = 0, v2 = 0, v3 = 0;
    if (i0 + 3 < N) {
        int4 v = *(const int4*)(counts + i0);
        v0 = v.x; v1 = v.y; v2 = v.z; v3 = v.w;
    } else {
        if (i0 + 0 < N) v0 = counts[i0 + 0];
        if (i0 + 1 < N) v1 = counts[i0 + 1];
        if (i0 + 2 < N) v2 = counts[i0 + 2];
        if (i0 + 3 < N) v3 = counts[i0 + 3];
    }
    int tt = v0 + v1 + v2 + v3;
    int incl = tt;
#pragma unroll
    for (int off = 1; off < 64; off <<= 1) {
        int t = __shfl_up(incl, off);
        if (lane >= off) incl += t;
    }
    __syncthreads();                 // wsums reuse
    if (lane == 63) wsums[wv] = incl;
    __syncthreads();
    int woff = 0;
    for (int w2 = 0; w2 < wv; ++w2) woff += wsums[w2];
    int base = base_s + woff + (incl - tt);
    if (i0 + 0 < N) rowptr[i0 + 0] = base;
    if (i0 + 1 < N) rowptr[i0 + 1] = base + v0;
    if (i0 + 2 < N) rowptr[i0 + 2] = base + v0 + v1;
    if (i0 + 3 < N) rowptr[i0 + 3] = base + v0 + v1 + v2;
    if (blockIdx.x == 0 && tid == 0) rowptr[N] = E;
}

// ---------------------------------------------------------------------------
// scatter: pos = rowptr[dst] + eslot[e]; write {ex0,ex1,ex2,src}. No atomics.
// Streams NT (ei/ef/eslot loads, rec store -> clean lines for agg's
// cross-XCD reads). Max-shift skipped: softmax shift-invariant, scores
// bounded, eps negligible.
// ---------------------------------------------------------------------------
__global__ __launch_bounds__(256) void scatter_kernel(const int* __restrict__ ei,
                                                      const float* __restrict__ ef,
                                                      const float* __restrict__ s1,
                                                      const float* __restrict__ s2,
                                                      const int* __restrict__ rowptr,
                                                      const int* __restrict__ eslot,
                                                      f32x4* __restrict__ rec, int E) {
    int e = blockIdx.x * blockDim.x + threadIdx.x;
    if (e >= E) return;
    int src = __builtin_nontemporal_load(ei + e);
    int dst = __builtin_nontemporal_load(ei + E + e);
    float s = s1[src] + s2[dst];
    s = (s >= 0.f) ? s : ALPHA * s;
    float f0 = __builtin_nontemporal_load(ef + e * 3 + 0);
    float f1 = __builtin_nontemporal_load(ef + e * 3 + 1);
    float f2 = __builtin_nontemporal_load(ef + e * 3 + 2);
    f32x4 r;
    r.x = __expf(s * f0);
    r.y = __expf(s * f1);
    r.z = __expf(s * f2);
    r.w = __int_as_float(src);
    int pos = rowptr[dst] + __builtin_nontemporal_load(eslot + e);
    __builtin_nontemporal_store(r, rec + pos);
}

// ---------------------------------------------------------------------------
// agg: one wave per node, atomic-free. Lane-parallel denominator pass +
// xor-butterfly. Main: x4-unrolled gather of bf16 Y rows (768B/edge, 12
// loads in flight — R4's best shape: VGPR 28, occ ~70%). rec loads + out
// stores NT so L2 stays reserved for Y.
// ---------------------------------------------------------------------------
__global__ __launch_bounds__(256) void agg_kernel(const f32x4* __restrict__ rec,
                                                  const int* __restrict__ rowptr,
                                                  const uint32* __restrict__ Yu,
                                                  float* __restrict__ out, int N) {
    int node = (blockIdx.x * blockDim.x + threadIdx.x) >> 6;
    int lane = threadIdx.x & 63;
    if (node >= N) return;
    int beg = rowptr[node], end = rowptr[node + 1];

    float d0 = 0.f, d1 = 0.f, d2 = 0.f;
    for (int jb = beg + lane; jb < end; jb += 64) {
        f32x4 r = __builtin_nontemporal_load(rec + jb);
        d0 += r.x; d1 += r.y; d2 += r.z;
    }
#pragma unroll
    for (int off = 32; off > 0; off >>= 1) {
        d0 += __shfl_xor(d0, off);
        d1 += __shfl_xor(d1, off);
        d2 += __shfl_xor(d2, off);
    }
    float inv0 = 1.f / (d0 + 1e-16f);
    float inv1 = 1.f / (d1 + 1e-16f);
    float inv2 = 1.f / (d2 + 1e-16f);

    float a0 = 0.f, a1 = 0.f;
    int j = beg;
    for (; j + 3 < end; j += 4) {
        f32x4 r0 = __builtin_nontemporal_load(rec + j);
        f32x4 r1 = __builtin_nontemporal_load(rec + j + 1);
        f32x4 r2 = __builtin_nontemporal_load(rec + j + 2);
        f32x4 r3 = __builtin_nontemporal_load(rec + j + 3);
        const uint32* p0 = Yu + (size_t)__float_as_int(r0.w) * 192;
        const uint32* p1 = Yu + (size_t)__float_as_int(r1.w) * 192;
        const uint32* p2 = Yu + (size_t)__float_as_int(r2.w) * 192;
        const uint32* p3 = Yu + (size_t)__float_as_int(r3.w) * 192;
        uint32 u00 = p0[lane], u01 = p0[64 + lane], u02 = p0[128 + lane];
        uint32 u10 = p1[lane], u11 = p1[64 + lane], u12 = p1[128 + lane];
        uint32 u20 = p2[lane], u21 = p2[64 + lane], u22 = p2[128 + lane];
        uint32 u30 = p3[lane], u31 = p3[64 + lane], u32 = p3[128 + lane];
        float w00 = r0.x * inv0, w01 = r0.y * inv1, w02 = r0.z * inv2;
        float w10 = r1.x * inv0, w11 = r1.y * inv1, w12 = r1.z * inv2;
        float w20 = r2.x * inv0, w21 = r2.y * inv1, w22 = r2.z * inv2;
        float w30 = r3.x * inv0, w31 = r3.y * inv1, w32 = r3.z * inv2;
        a0 += w00 * bflo(u00) + w01 * bflo(u01) + w02 * bflo(u02);
        a1 += w00 * bfhi(u00) + w01 * bfhi(u01) + w02 * bfhi(u02);
        a0 += w10 * bflo(u10) + w11 * bflo(u11) + w12 * bflo(u12);
        a1 += w10 * bfhi(u10) + w11 * bfhi(u11) + w12 * bfhi(u12);
        a0 += w20 * bflo(u20) + w21 * bflo(u21) + w22 * bflo(u22);
        a1 += w20 * bfhi(u20) + w21 * bfhi(u21) + w22 * bfhi(u22);
        a0 += w30 * bflo(u30) + w31 * bflo(u31) + w32 * bflo(u32);
        a1 += w30 * bfhi(u30) + w31 * bfhi(u31) + w32 * bfhi(u32);
    }
    for (; j < end; ++j) {
        f32x4 r0 = __builtin_nontemporal_load(rec + j);
        const uint32* p0 = Yu + (size_t)__float_as_int(r0.w) * 192;
        uint32 u00 = p0[lane], u01 = p0[64 + lane], u02 = p0[128 + lane];
        float w00 = r0.x * inv0, w01 = r0.y * inv1, w02 = r0.z * inv2;
        a0 += w00 * bflo(u00) + w01 * bflo(u01) + w02 * bflo(u02);
        a1 += w00 * bfhi(u00) + w01 * bfhi(u01) + w02 * bfhi(u02);
    }
    f32x2 o; o.x = a0; o.y = a1;
    __builtin_nontemporal_store(o, (f32x2*)(out + (size_t)node * 128) + lane);
}

// ---------------------------------------------------------------------------
extern "C" void kernel_launch(void* const* d_in, const int* in_sizes, int n_in,
                              void* d_out, int out_size, void* d_ws, size_t ws_size,
                              hipStream_t stream) {
    const float* h    = (const float*)d_in[0];
    const int*   ei   = (const int*)d_in[1];    // [2, E]
    const float* ef   = (const float*)d_in[2];  // [E, 3]
    const float* W    = (const float*)d_in[3];  // [128,128]
    const float* a1   = (const float*)d_in[4];  // [128]
    const float* a2   = (const float*)d_in[5];  // [128]
    const float* Wout = (const float*)d_in[6];  // [384,128]
    float*       out  = (float*)d_out;

    const int N = in_sizes[0] / 128;  // 50000
    const int E = in_sizes[2] / 3;    // 800000
    const int nchunk = (N + 1023) / 1024;

    // workspace layout (rec first -> 16B alignment for everything vectorized)
    f32x4* rec = (f32x4*)d_ws;                          // E * 16B
    unsigned short* Yb  = (unsigned short*)(rec + E);   // N*384 bf16
    unsigned short* WT2 = Yb + (size_t)N * 384;         // 3*128*128 bf16
    float* w1f  = (float*)(WT2 + 3 * 128 * 128);        // 128
    float* w2f  = w1f + 128;                            // 128
    float* s1   = w2f + 128;                            // N
    float* s2   = s1 + N;                               // N
    int* counts = (int*)(s2 + N);                       // N
    int* rowptr = counts + N;                           // N+1
    int* eslot  = rowptr + N + 1;                       // E

    (void)hipMemsetAsync(counts, 0, (size_t)N * sizeof(int), stream);

    hist_kernel<<<(E + 255) / 256, 256, 0, stream>>>(ei, counts, eslot, E);
    prep2_kernel<<<25, 256, 0, stream>>>(W, Wout, a1, a2, WT2, w1f, w2f);
    mmy2_kernel<<<(N + 127) / 128, 256, 0, stream>>>(h, WT2, w1f, w2f, Yb, s1, s2, N);
    scan_fused_kernel<<<nchunk, 256, 0, stream>>>(counts, rowptr, N, E);
    scatter_kernel<<<(E + 255) / 256, 256, 0, stream>>>(ei, ef, s1, s2, rowptr, eslot, rec, E);
    agg_kernel<<<(N * 64 + 255) / 256, 256, 0, stream>>>(rec, rowptr, (const uint32*)Yb, out, N);
}

// Round 8
// 258.377 us; speedup vs baseline: 1.0934x; 1.0934x over previous
//
#include <hip/hip_runtime.h>
#include <hip/hip_bf16.h>

#define ALPHA 0.2f
typedef unsigned int uint32;
typedef __attribute__((ext_vector_type(8))) short short8;   // 8 bf16 = 4 VGPRs
typedef __attribute__((ext_vector_type(4))) float f32x4;

static __device__ __forceinline__ unsigned short f2bf(float f) {
    unsigned int u = __float_as_uint(f);
    u += 0x7fffu + ((u >> 16) & 1u);          // RNE
    return (unsigned short)(u >> 16);
}
static __device__ __forceinline__ uint32 pk2bf(float lo, float hi) {
    return (uint32)f2bf(lo) | ((uint32)f2bf(hi) << 16);
}
static __device__ __forceinline__ float bflo(uint32 u) { return __uint_as_float(u << 16); }
static __device__ __forceinline__ float bfhi(uint32 u) { return __uint_as_float(u & 0xffff0000u); }

// ---------------------------------------------------------------------------
// K1 = hist (blocks 0..nbh-1) ∥ prep (blocks nbh..nbh+24).
// hist: counts[dst]++ per edge, record slot-within-node.
// prep: fold W into downstream (Y_k = h@(W@Wout_k), s = h@(W@a));
//   blocks bp<24: WT2[s][n][j] = bf16(sum_c W[j][c]*Wout[s*128+c][n])
//   block bp==24: w1f[j] = sum_c W[j][c]*a1[c], w2f likewise.
// prep uses only 8KB LDS (W rows direct from global/L1; 25 blocks of slack
// work hidden under hist) so hist occupancy is unaffected.
// ---------------------------------------------------------------------------
__global__ __launch_bounds__(256) void k1_hist_prep(const int* __restrict__ ei,
                                                    int* __restrict__ counts,
                                                    int* __restrict__ eslot, int E,
                                                    const float* __restrict__ W,
                                                    const float* __restrict__ Wout,
                                                    const float* __restrict__ a1,
                                                    const float* __restrict__ a2,
                                                    unsigned short* __restrict__ WT2,
                                                    float* __restrict__ w1f,
                                                    float* __restrict__ w2f, int nbh) {
    __shared__ float Wos[128 * 16];       // [c][q] Wout slice cols (prep only)
    const int tid = threadIdx.x;
    if ((int)blockIdx.x < nbh) {
        int e = blockIdx.x * 256 + tid;
        if (e < E) eslot[e] = atomicAdd(&counts[ei[E + e]], 1);
        return;
    }
    int bp = blockIdx.x - nbh;
    if (bp < 24) {
        int s = bp >> 3, nb = bp & 7;
        for (int i = tid; i < 2048; i += 256) {
            int c = i >> 4, q = i & 15;
            Wos[i] = Wout[(size_t)(s * 128 + c) * 128 + nb * 16 + q];
        }
        __syncthreads();
        int j = tid & 127, nh = tid >> 7;
        float acc[8];
#pragma unroll
        for (int p = 0; p < 8; ++p) acc[p] = 0.f;
        for (int c = 0; c < 128; ++c) {
            float w = W[j * 128 + c];     // L1-resident after first touch
#pragma unroll
            for (int p = 0; p < 8; ++p) acc[p] += w * Wos[c * 16 + nh * 8 + p];
        }
#pragma unroll
        for (int p = 0; p < 8; ++p) {
            int n = nb * 16 + nh * 8 + p;
            WT2[((size_t)s * 128 + n) * 128 + j] = f2bf(acc[p]);
        }
    } else {
        if (tid < 128) {
            float acc1 = 0.f, acc2 = 0.f;
            for (int c = 0; c < 128; ++c) {
                float w = W[tid * 128 + c];
                acc1 += w * a1[c];
                acc2 += w * a2[c];
            }
            w1f[tid] = acc1;
            w2f[tid] = acc2;
        }
    }
}

// ---------------------------------------------------------------------------
// K2 = mmy (blocks 0..nbm-1) ∥ scan (blocks nbm..nbm+nchunk-1).
// mmy: Yb[M,384] = bf16(h) @ M_k (3 slices) via 16x16x32 bf16 MFMA.
//   64-row tiles (As 16KB + Bs 32KB + misc ≈ 49KB -> 3 blocks/CU), s1/s2
//   fused fp32 into the A-staging pass. XOR-swizzled 16B groups.
// scan: rowptr from counts; each block re-reduces the preceding counts from
//   L2 for its base, then scans its own 1024-chunk.
// ---------------------------------------------------------------------------
__global__ __launch_bounds__(256) void k2_mmy_scan(const float* __restrict__ h,
                                                   const unsigned short* __restrict__ WT2,
                                                   const float* __restrict__ w1f,
                                                   const float* __restrict__ w2f,
                                                   unsigned short* __restrict__ Yb,
                                                   float* __restrict__ s1,
                                                   float* __restrict__ s2, int M,
                                                   const int* __restrict__ counts,
                                                   int* __restrict__ rowptr,
                                                   int N, int E, int nbm) {
    __shared__ unsigned short As[64 * 128];   // 16KB
    __shared__ unsigned short Bs[128 * 128];  // 32KB
    __shared__ float ws1[128], ws2[128];
    __shared__ int wsums[4];
    __shared__ int base_s;
    const int tid = threadIdx.x;

    if ((int)blockIdx.x >= nbm) {
        // ---------------- scan ----------------
        const int bs   = blockIdx.x - nbm;
        const int lane = tid & 63, wv = tid >> 6;
        const int limit = bs * 1024;
        int acc = 0;
        for (int i = tid * 4; i < limit; i += 1024) {
            int4 v = *(const int4*)(counts + i);
            acc += v.x + v.y + v.z + v.w;
        }
#pragma unroll
        for (int off = 32; off > 0; off >>= 1) acc += __shfl_down(acc, off);
        if (lane == 0) wsums[wv] = acc;
        __syncthreads();
        if (tid == 0) base_s = wsums[0] + wsums[1] + wsums[2] + wsums[3];
        __syncthreads();
        int i0 = bs * 1024 + tid * 4;
        int v0 = 0, v1 = 0, v2 = 0, v3 = 0;
        if (i0 + 3 < N) {
            int4 v = *(const int4*)(counts + i0);
            v0 = v.x; v1 = v.y; v2 = v.z; v3 = v.w;
        } else {
            if (i0 + 0 < N) v0 = counts[i0 + 0];
            if (i0 + 1 < N) v1 = counts[i0 + 1];
            if (i0 + 2 < N) v2 = counts[i0 + 2];
            if (i0 + 3 < N) v3 = counts[i0 + 3];
        }
        int tt = v0 + v1 + v2 + v3;
        int incl = tt;
#pragma unroll
        for (int off = 1; off < 64; off <<= 1) {
            int t = __shfl_up(incl, off);
            if (lane >= off) incl += t;
        }
        __syncthreads();
        if (lane == 63) wsums[wv] = incl;
        __syncthreads();
        int woff = 0;
        for (int w2 = 0; w2 < wv; ++w2) woff += wsums[w2];
        int base = base_s + woff + (incl - tt);
        if (i0 + 0 < N) rowptr[i0 + 0] = base;
        if (i0 + 1 < N) rowptr[i0 + 1] = base + v0;
        if (i0 + 2 < N) rowptr[i0 + 2] = base + v0 + v1;
        if (i0 + 3 < N) rowptr[i0 + 3] = base + v0 + v1 + v2;
        if (bs == 0 && tid == 0) rowptr[N] = E;
        return;
    }

    // ---------------- mmy (64-row tile) ----------------
    const int lane = tid & 63;
    const int w    = tid >> 6;
    const int row0 = blockIdx.x * 64;

    if (tid < 128) ws1[tid] = w1f[tid];
    else           ws2[tid - 128] = w2f[tid - 128];
    __syncthreads();

    // stage A (fp32 -> bf16) + fused fp32 score partials
    const float4* h4 = (const float4*)h;
    float sp1[4], sp2[4];
#pragma unroll
    for (int m = 0; m < 4; ++m) { sp1[m] = 0.f; sp2[m] = 0.f; }
#pragma unroll
    for (int m = 0; m < 4; ++m) {
        int i = m * 256 + tid;            // 0..1023
        int r = i >> 4, g = i & 15;       // r = m*16 + (tid>>4), g = tid&15
        int rg = row0 + r;
        float4 va = make_float4(0.f, 0.f, 0.f, 0.f), vb = va;
        if (rg < M) {
            va = h4[(size_t)rg * 32 + g * 2];
            vb = h4[(size_t)rg * 32 + g * 2 + 1];
        }
        float4 wa1 = *(const float4*)(ws1 + g * 8);
        float4 wb1 = *(const float4*)(ws1 + g * 8 + 4);
        float4 wa2 = *(const float4*)(ws2 + g * 8);
        float4 wb2 = *(const float4*)(ws2 + g * 8 + 4);
        sp1[m] += va.x * wa1.x + va.y * wa1.y + va.z * wa1.z + va.w * wa1.w
                + vb.x * wb1.x + vb.y * wb1.y + vb.z * wb1.z + vb.w * wb1.w;
        sp2[m] += va.x * wa2.x + va.y * wa2.y + va.z * wa2.z + va.w * wa2.w
                + vb.x * wb2.x + vb.y * wb2.y + vb.z * wb2.z + vb.w * wb2.w;
        uint4 u;
        u.x = pk2bf(va.x, va.y); u.y = pk2bf(va.z, va.w);
        u.z = pk2bf(vb.x, vb.y); u.w = pk2bf(vb.z, vb.w);
        *(uint4*)(As + r * 128 + ((g ^ (r & 15)) * 8)) = u;
    }
#pragma unroll
    for (int m = 0; m < 4; ++m) {
#pragma unroll
        for (int off = 1; off < 16; off <<= 1) {
            sp1[m] += __shfl_xor(sp1[m], off);
            sp2[m] += __shfl_xor(sp2[m], off);
        }
    }
    if ((tid & 15) == 0) {
#pragma unroll
        for (int m = 0; m < 4; ++m) {
            int rg = row0 + m * 16 + (tid >> 4);
            if (rg < M) { s1[rg] = sp1[m]; s2[rg] = sp2[m]; }
        }
    }

    const int ml   = lane & 15;
    const int quad = lane >> 4;
    for (int ks = 0; ks < 3; ++ks) {
        __syncthreads();                  // As ready / prev Bs reads done
#pragma unroll
        for (int m = 0; m < 8; ++m) {     // stage Bs = WT2[ks] (128 n-rows)
            int i = m * 256 + tid;
            int n = i >> 4, g = i & 15;
            uint4 v = *(const uint4*)(WT2 + (size_t)ks * 16384 + n * 128 + g * 8);
            *(uint4*)(Bs + n * 128 + ((g ^ (n & 15)) * 8)) = v;
        }
        __syncthreads();

        f32x4 acc[8];
#pragma unroll
        for (int nt = 0; nt < 8; ++nt) acc[nt] = (f32x4){0.f, 0.f, 0.f, 0.f};
#pragma unroll
        for (int kc = 0; kc < 4; ++kc) {
            int gl = ((kc * 4 + quad) ^ ml) * 8;
            short8 af = *(const short8*)(As + (w * 16 + ml) * 128 + gl);
#pragma unroll
            for (int nt = 0; nt < 8; ++nt) {
                short8 bf = *(const short8*)(Bs + (nt * 16 + ml) * 128 + gl);
                acc[nt] = __builtin_amdgcn_mfma_f32_16x16x32_bf16(af, bf, acc[nt], 0, 0, 0);
            }
        }
        int rbase = row0 + w * 16 + quad * 4;
#pragma unroll
        for (int r = 0; r < 4; ++r) {
            int rg = rbase + r;
            if (rg >= M) continue;
            unsigned short* yrow = Yb + (size_t)rg * 384 + ks * 128 + ml;
#pragma unroll
            for (int nt = 0; nt < 8; ++nt)
                yrow[nt * 16] = f2bf(acc[nt][r]);
        }
    }
}

// ---------------------------------------------------------------------------
// scatter: pos = rowptr[dst] + eslot[e]; write {ex0,ex1,ex2,src}. No atomics.
// Max-shift skipped: softmax shift-invariant, scores bounded, eps negligible.
// ---------------------------------------------------------------------------
__global__ __launch_bounds__(256) void scatter_kernel(const int* __restrict__ ei,
                                                      const float* __restrict__ ef,
                                                      const float* __restrict__ s1,
                                                      const float* __restrict__ s2,
                                                      const int* __restrict__ rowptr,
                                                      const int* __restrict__ eslot,
                                                      float4* __restrict__ rec, int E) {
    int e = blockIdx.x * blockDim.x + threadIdx.x;
    if (e >= E) return;
    int src = ei[e];
    int dst = ei[E + e];
    float s = s1[src] + s2[dst];
    s = (s >= 0.f) ? s : ALPHA * s;
    float ex0 = __expf(s * ef[e * 3 + 0]);
    float ex1 = __expf(s * ef[e * 3 + 1]);
    float ex2 = __expf(s * ef[e * 3 + 2]);
    int pos = rowptr[dst] + eslot[e];
    rec[pos] = make_float4(ex0, ex1, ex2, __int_as_float(src));
}

// ---------------------------------------------------------------------------
// agg: one wave per node, atomic-free (R5's proven 83.5µs shape: x4 unroll,
// VGPR~28, plain loads — NT hurt it, reverted). Lane-parallel denominator
// pass + xor-butterfly; x4-unrolled bf16 Y gather; one float2 store/lane.
// ---------------------------------------------------------------------------
__global__ __launch_bounds__(256) void agg_kernel(const float4* __restrict__ rec,
                                                  const int* __restrict__ rowptr,
                                                  const uint32* __restrict__ Yu,
                                                  float* __restrict__ out, int N) {
    int node = (blockIdx.x * blockDim.x + threadIdx.x) >> 6;
    int lane = threadIdx.x & 63;
    if (node >= N) return;
    int beg = rowptr[node], end = rowptr[node + 1];

    float d0 = 0.f, d1 = 0.f, d2 = 0.f;
    for (int jb = beg + lane; jb < end; jb += 64) {
        float4 r = rec[jb];
        d0 += r.x; d1 += r.y; d2 += r.z;
    }
#pragma unroll
    for (int off = 32; off > 0; off >>= 1) {
        d0 += __shfl_xor(d0, off);
        d1 += __shfl_xor(d1, off);
        d2 += __shfl_xor(d2, off);
    }
    float inv0 = 1.f / (d0 + 1e-16f);
    float inv1 = 1.f / (d1 + 1e-16f);
    float inv2 = 1.f / (d2 + 1e-16f);

    float a0 = 0.f, a1 = 0.f;
    int j = beg;
    for (; j + 3 < end; j += 4) {
        float4 r0 = rec[j], r1 = rec[j + 1], r2 = rec[j + 2], r3 = rec[j + 3];
        const uint32* p0 = Yu + (size_t)__float_as_int(r0.w) * 192;
        const uint32* p1 = Yu + (size_t)__float_as_int(r1.w) * 192;
        const uint32* p2 = Yu + (size_t)__float_as_int(r2.w) * 192;
        const uint32* p3 = Yu + (size_t)__float_as_int(r3.w) * 192;
        uint32 u00 = p0[lane], u01 = p0[64 + lane], u02 = p0[128 + lane];
        uint32 u10 = p1[lane], u11 = p1[64 + lane], u12 = p1[128 + lane];
        uint32 u20 = p2[lane], u21 = p2[64 + lane], u22 = p2[128 + lane];
        uint32 u30 = p3[lane], u31 = p3[64 + lane], u32 = p3[128 + lane];
        float w00 = r0.x * inv0, w01 = r0.y * inv1, w02 = r0.z * inv2;
        float w10 = r1.x * inv0, w11 = r1.y * inv1, w12 = r1.z * inv2;
        float w20 = r2.x * inv0, w21 = r2.y * inv1, w22 = r2.z * inv2;
        float w30 = r3.x * inv0, w31 = r3.y * inv1, w32 = r3.z * inv2;
        a0 += w00 * bflo(u00) + w01 * bflo(u01) + w02 * bflo(u02);
        a1 += w00 * bfhi(u00) + w01 * bfhi(u01) + w02 * bfhi(u02);
        a0 += w10 * bflo(u10) + w11 * bflo(u11) + w12 * bflo(u12);
        a1 += w10 * bfhi(u10) + w11 * bfhi(u11) + w12 * bfhi(u12);
        a0 += w20 * bflo(u20) + w21 * bflo(u21) + w22 * bflo(u22);
        a1 += w20 * bfhi(u20) + w21 * bfhi(u21) + w22 * bfhi(u22);
        a0 += w30 * bflo(u30) + w31 * bflo(u31) + w32 * bflo(u32);
        a1 += w30 * bfhi(u30) + w31 * bfhi(u31) + w32 * bfhi(u32);
    }
    for (; j < end; ++j) {
        float4 r0 = rec[j];
        const uint32* p0 = Yu + (size_t)__float_as_int(r0.w) * 192;
        uint32 u00 = p0[lane], u01 = p0[64 + lane], u02 = p0[128 + lane];
        float w00 = r0.x * inv0, w01 = r0.y * inv1, w02 = r0.z * inv2;
        a0 += w00 * bflo(u00) + w01 * bflo(u01) + w02 * bflo(u02);
        a1 += w00 * bfhi(u00) + w01 * bfhi(u01) + w02 * bfhi(u02);
    }
    ((float2*)(out + (size_t)node * 128))[lane] = make_float2(a0, a1);
}

// ---------------------------------------------------------------------------
extern "C" void kernel_launch(void* const* d_in, const int* in_sizes, int n_in,
                              void* d_out, int out_size, void* d_ws, size_t ws_size,
                              hipStream_t stream) {
    const float* h    = (const float*)d_in[0];
    const int*   ei   = (const int*)d_in[1];    // [2, E]
    const float* ef   = (const float*)d_in[2];  // [E, 3]
    const float* W    = (const float*)d_in[3];  // [128,128]
    const float* a1   = (const float*)d_in[4];  // [128]
    const float* a2   = (const float*)d_in[5];  // [128]
    const float* Wout = (const float*)d_in[6];  // [384,128]
    float*       out  = (float*)d_out;

    const int N = in_sizes[0] / 128;  // 50000
    const int E = in_sizes[2] / 3;    // 800000
    const int nchunk = (N + 1023) / 1024;
    const int nbh    = (E + 255) / 256;   // hist blocks
    const int nbm    = (N + 63) / 64;     // mmy blocks

    // workspace layout (rec first -> 16B alignment for everything vectorized)
    float4* rec = (float4*)d_ws;                        // E * 16B
    unsigned short* Yb  = (unsigned short*)(rec + E);   // N*384 bf16
    unsigned short* WT2 = Yb + (size_t)N * 384;         // 3*128*128 bf16
    float* w1f  = (float*)(WT2 + 3 * 128 * 128);        // 128
    float* w2f  = w1f + 128;                            // 128
    float* s1   = w2f + 128;                            // N
    float* s2   = s1 + N;                               // N
    int* counts = (int*)(s2 + N);                       // N
    int* rowptr = counts + N;                           // N+1
    int* eslot  = rowptr + N + 1;                       // E

    (void)hipMemsetAsync(counts, 0, (size_t)N * sizeof(int), stream);

    k1_hist_prep<<<nbh + 25, 256, 0, stream>>>(ei, counts, eslot, E,
                                               W, Wout, a1, a2, WT2, w1f, w2f, nbh);
    k2_mmy_scan<<<nbm + nchunk, 256, 0, stream>>>(h, WT2, w1f, w2f, Yb, s1, s2, N,
                                                  counts, rowptr, N, E, nbm);
    scatter_kernel<<<(E + 255) / 256, 256, 0, stream>>>(ei, ef, s1, s2, rowptr, eslot, rec, E);
    agg_kernel<<<(N * 64 + 255) / 256, 256, 0, stream>>>(rec, rowptr, (const uint32*)Yb, out, N);
}

// Round 9
// 248.849 us; speedup vs baseline: 1.1352x; 1.0383x over previous
//
#include <hip/hip_runtime.h>
#include <hip/hip_bf16.h>

#define ALPHA 0.2f
typedef unsigned int uint32;
typedef __attribute__((ext_vector_type(8))) short short8;   // 8 bf16 = 4 VGPRs
typedef __attribute__((ext_vector_type(4))) float f32x4;

static __device__ __forceinline__ unsigned short f2bf(float f) {
    unsigned int u = __float_as_uint(f);
    u += 0x7fffu + ((u >> 16) & 1u);          // RNE
    return (unsigned short)(u >> 16);
}
static __device__ __forceinline__ uint32 pk2bf(float lo, float hi) {
    return (uint32)f2bf(lo) | ((uint32)f2bf(hi) << 16);
}
static __device__ __forceinline__ float bflo(uint32 u) { return __uint_as_float(u << 16); }
static __device__ __forceinline__ float bfhi(uint32 u) { return __uint_as_float(u & 0xffff0000u); }

// ---------------------------------------------------------------------------
// K1 = hist (blocks 0..nbh-1) ∥ prep (blocks nbh..nbh+24).
// hist: counts[dst]++ per edge, record slot-within-node.
// prep: fold W into downstream (Y_k = h@(W@Wout_k), s = h@(W@a)).
// ---------------------------------------------------------------------------
__global__ __launch_bounds__(256) void k1_hist_prep(const int* __restrict__ ei,
                                                    int* __restrict__ counts,
                                                    int* __restrict__ eslot, int E,
                                                    const float* __restrict__ W,
                                                    const float* __restrict__ Wout,
                                                    const float* __restrict__ a1,
                                                    const float* __restrict__ a2,
                                                    unsigned short* __restrict__ WT2,
                                                    float* __restrict__ w1f,
                                                    float* __restrict__ w2f, int nbh) {
    __shared__ float Wos[128 * 16];       // [c][q] Wout slice cols (prep only)
    const int tid = threadIdx.x;
    if ((int)blockIdx.x < nbh) {
        int e = blockIdx.x * 256 + tid;
        if (e < E) eslot[e] = atomicAdd(&counts[ei[E + e]], 1);
        return;
    }
    int bp = blockIdx.x - nbh;
    if (bp < 24) {
        int s = bp >> 3, nb = bp & 7;
        for (int i = tid; i < 2048; i += 256) {
            int c = i >> 4, q = i & 15;
            Wos[i] = Wout[(size_t)(s * 128 + c) * 128 + nb * 16 + q];
        }
        __syncthreads();
        int j = tid & 127, nh = tid >> 7;
        float acc[8];
#pragma unroll
        for (int p = 0; p < 8; ++p) acc[p] = 0.f;
        for (int c = 0; c < 128; ++c) {
            float w = W[j * 128 + c];     // L1-resident after first touch
#pragma unroll
            for (int p = 0; p < 8; ++p) acc[p] += w * Wos[c * 16 + nh * 8 + p];
        }
#pragma unroll
        for (int p = 0; p < 8; ++p) {
            int n = nb * 16 + nh * 8 + p;
            WT2[((size_t)s * 128 + n) * 128 + j] = f2bf(acc[p]);
        }
    } else {
        if (tid < 128) {
            float acc1 = 0.f, acc2 = 0.f;
            for (int c = 0; c < 128; ++c) {
                float w = W[tid * 128 + c];
                acc1 += w * a1[c];
                acc2 += w * a2[c];
            }
            w1f[tid] = acc1;
            w2f[tid] = acc2;
        }
    }
}

// ---------------------------------------------------------------------------
// K2 = mmy (blocks 0..nbm-1) ∥ scan (blocks nbm..).
// mmy: 64-row tiles, 16x16x32 bf16 MFMA, s1/s2 fused in A-staging.
//   NEW epilogue: acc -> LDS (reuse Bs, stride 136 shorts = 16B-aligned rows)
//   -> coalesced uint4 stores (12 per thread total vs 96 scalar b16 stores).
// scan: rowptr from counts (self-basing re-reduction, L2-resident).
// ---------------------------------------------------------------------------
__global__ __launch_bounds__(256) void k2_mmy_scan(const float* __restrict__ h,
                                                   const unsigned short* __restrict__ WT2,
                                                   const float* __restrict__ w1f,
                                                   const float* __restrict__ w2f,
                                                   unsigned short* __restrict__ Yb,
                                                   float* __restrict__ s1,
                                                   float* __restrict__ s2, int M,
                                                   const int* __restrict__ counts,
                                                   int* __restrict__ rowptr,
                                                   int N, int E, int nbm) {
    __shared__ unsigned short As[64 * 128];   // 16KB
    __shared__ unsigned short Bs[128 * 128];  // 32KB (also epilogue transpose buf)
    __shared__ float ws1[128], ws2[128];
    __shared__ int wsums[4];
    __shared__ int base_s;
    const int tid = threadIdx.x;

    if ((int)blockIdx.x >= nbm) {
        // ---------------- scan ----------------
        const int bs   = blockIdx.x - nbm;
        const int lane = tid & 63, wv = tid >> 6;
        const int limit = bs * 1024;
        int acc = 0;
        for (int i = tid * 4; i < limit; i += 1024) {
            int4 v = *(const int4*)(counts + i);
            acc += v.x + v.y + v.z + v.w;
        }
#pragma unroll
        for (int off = 32; off > 0; off >>= 1) acc += __shfl_down(acc, off);
        if (lane == 0) wsums[wv] = acc;
        __syncthreads();
        if (tid == 0) base_s = wsums[0] + wsums[1] + wsums[2] + wsums[3];
        __syncthreads();
        int i0 = bs * 1024 + tid * 4;
        int v0 = 0, v1 = 0, v2 = 0, v3 = 0;
        if (i0 + 3 < N) {
            int4 v = *(const int4*)(counts + i0);
            v0 = v.x; v1 = v.y; v2 = v.z; v3 = v.w;
        } else {
            if (i0 + 0 < N) v0 = counts[i0 + 0];
            if (i0 + 1 < N) v1 = counts[i0 + 1];
            if (i0 + 2 < N) v2 = counts[i0 + 2];
            if (i0 + 3 < N) v3 = counts[i0 + 3];
        }
        int tt = v0 + v1 + v2 + v3;
        int incl = tt;
#pragma unroll
        for (int off = 1; off < 64; off <<= 1) {
            int t = __shfl_up(incl, off);
            if (lane >= off) incl += t;
        }
        __syncthreads();
        if (lane == 63) wsums[wv] = incl;
        __syncthreads();
        int woff = 0;
        for (int w2 = 0; w2 < wv; ++w2) woff += wsums[w2];
        int base = base_s + woff + (incl - tt);
        if (i0 + 0 < N) rowptr[i0 + 0] = base;
        if (i0 + 1 < N) rowptr[i0 + 1] = base + v0;
        if (i0 + 2 < N) rowptr[i0 + 2] = base + v0 + v1;
        if (i0 + 3 < N) rowptr[i0 + 3] = base + v0 + v1 + v2;
        if (bs == 0 && tid == 0) rowptr[N] = E;
        return;
    }

    // ---------------- mmy (64-row tile) ----------------
    const int lane = tid & 63;
    const int w    = tid >> 6;
    const int row0 = blockIdx.x * 64;

    if (tid < 128) ws1[tid] = w1f[tid];
    else           ws2[tid - 128] = w2f[tid - 128];
    __syncthreads();

    // stage A (fp32 -> bf16) + fused fp32 score partials
    const float4* h4 = (const float4*)h;
    float sp1[4], sp2[4];
#pragma unroll
    for (int m = 0; m < 4; ++m) { sp1[m] = 0.f; sp2[m] = 0.f; }
#pragma unroll
    for (int m = 0; m < 4; ++m) {
        int i = m * 256 + tid;            // 0..1023
        int r = i >> 4, g = i & 15;
        int rg = row0 + r;
        float4 va = make_float4(0.f, 0.f, 0.f, 0.f), vb = va;
        if (rg < M) {
            va = h4[(size_t)rg * 32 + g * 2];
            vb = h4[(size_t)rg * 32 + g * 2 + 1];
        }
        float4 wa1 = *(const float4*)(ws1 + g * 8);
        float4 wb1 = *(const float4*)(ws1 + g * 8 + 4);
        float4 wa2 = *(const float4*)(ws2 + g * 8);
        float4 wb2 = *(const float4*)(ws2 + g * 8 + 4);
        sp1[m] += va.x * wa1.x + va.y * wa1.y + va.z * wa1.z + va.w * wa1.w
                + vb.x * wb1.x + vb.y * wb1.y + vb.z * wb1.z + vb.w * wb1.w;
        sp2[m] += va.x * wa2.x + va.y * wa2.y + va.z * wa2.z + va.w * wa2.w
                + vb.x * wb2.x + vb.y * wb2.y + vb.z * wb2.z + vb.w * wb2.w;
        uint4 u;
        u.x = pk2bf(va.x, va.y); u.y = pk2bf(va.z, va.w);
        u.z = pk2bf(vb.x, vb.y); u.w = pk2bf(vb.z, vb.w);
        *(uint4*)(As + r * 128 + ((g ^ (r & 15)) * 8)) = u;
    }
#pragma unroll
    for (int m = 0; m < 4; ++m) {
#pragma unroll
        for (int off = 1; off < 16; off <<= 1) {
            sp1[m] += __shfl_xor(sp1[m], off);
            sp2[m] += __shfl_xor(sp2[m], off);
        }
    }
    if ((tid & 15) == 0) {
#pragma unroll
        for (int m = 0; m < 4; ++m) {
            int rg = row0 + m * 16 + (tid >> 4);
            if (rg < M) { s1[rg] = sp1[m]; s2[rg] = sp2[m]; }
        }
    }

    const int ml   = lane & 15;
    const int quad = lane >> 4;
    for (int ks = 0; ks < 3; ++ks) {
        __syncthreads();                  // prev epilogue reads done / As ready
#pragma unroll
        for (int m = 0; m < 8; ++m) {     // stage Bs = WT2[ks] (128 n-rows)
            int i = m * 256 + tid;
            int n = i >> 4, g = i & 15;
            uint4 v = *(const uint4*)(WT2 + (size_t)ks * 16384 + n * 128 + g * 8);
            *(uint4*)(Bs + n * 128 + ((g ^ (n & 15)) * 8)) = v;
        }
        __syncthreads();

        f32x4 acc[8];
#pragma unroll
        for (int nt = 0; nt < 8; ++nt) acc[nt] = (f32x4){0.f, 0.f, 0.f, 0.f};
#pragma unroll
        for (int kc = 0; kc < 4; ++kc) {
            int gl = ((kc * 4 + quad) ^ ml) * 8;
            short8 af = *(const short8*)(As + (w * 16 + ml) * 128 + gl);
#pragma unroll
            for (int nt = 0; nt < 8; ++nt) {
                short8 bf = *(const short8*)(Bs + (nt * 16 + ml) * 128 + gl);
                acc[nt] = __builtin_amdgcn_mfma_f32_16x16x32_bf16(af, bf, acc[nt], 0, 0, 0);
            }
        }
        // epilogue: acc -> Ct (=Bs, free now) -> coalesced uint4 stores
        __syncthreads();                  // all waves done reading Bs
        unsigned short* Ct = Bs;          // stride 136 shorts (272B, 16B-aligned)
        int lrow = w * 16 + quad * 4;
#pragma unroll
        for (int r = 0; r < 4; ++r)
#pragma unroll
            for (int nt = 0; nt < 8; ++nt)
                Ct[(lrow + r) * 136 + nt * 16 + ml] = f2bf(acc[nt][r]);
        __syncthreads();
#pragma unroll
        for (int m = 0; m < 4; ++m) {
            int i = m * 256 + tid;        // 0..1023
            int r2 = i >> 4, g = i & 15;
            int rg = row0 + r2;
            uint4 v = *(const uint4*)(Ct + r2 * 136 + g * 8);
            if (rg < M)
                *(uint4*)(Yb + (size_t)rg * 384 + ks * 128 + g * 8) = v;
        }
    }
}

// ---------------------------------------------------------------------------
// scatter: pos = rowptr[dst] + eslot[e]; write 8B record
// {src:17b | ex0:15b, ex1:15b | ex2:15b<<15} — ex>0 always so the bf16 sign
// bit is free; halves the random-write traffic vs 16B records.
// Max-shift skipped: softmax shift-invariant, scores bounded, eps negligible.
// ---------------------------------------------------------------------------
__global__ __launch_bounds__(256) void scatter_kernel(const int* __restrict__ ei,
                                                      const float* __restrict__ ef,
                                                      const float* __restrict__ s1,
                                                      const float* __restrict__ s2,
                                                      const int* __restrict__ rowptr,
                                                      const int* __restrict__ eslot,
                                                      uint2* __restrict__ rec8, int E) {
    int e = blockIdx.x * blockDim.x + threadIdx.x;
    if (e >= E) return;
    int src = ei[e];
    int dst = ei[E + e];
    float s = s1[src] + s2[dst];
    s = (s >= 0.f) ? s : ALPHA * s;
    unsigned short b0 = f2bf(__expf(s * ef[e * 3 + 0]));
    unsigned short b1 = f2bf(__expf(s * ef[e * 3 + 1]));
    unsigned short b2 = f2bf(__expf(s * ef[e * 3 + 2]));
    uint2 rv;
    rv.x = (uint32)src | ((uint32)(b0 & 0x7fffu) << 17);
    rv.y = (uint32)(b1 & 0x7fffu) | ((uint32)(b2 & 0x7fffu) << 15);
    int pos = rowptr[dst] + eslot[e];
    rec8[pos] = rv;
}

// ---------------------------------------------------------------------------
// agg: one wave per node, atomic-free (R5/R8 proven shape: x4 unroll, plain
// loads). 8B records decoded with 2 ops/value. Lane-parallel denom pass +
// xor-butterfly; x4-unrolled bf16 Y gather; one float2 store per lane.
// ---------------------------------------------------------------------------
__global__ __launch_bounds__(256) void agg_kernel(const uint2* __restrict__ rec8,
                                                  const int* __restrict__ rowptr,
                                                  const uint32* __restrict__ Yu,
                                                  float* __restrict__ out, int N) {
    int node = (blockIdx.x * blockDim.x + threadIdx.x) >> 6;
    int lane = threadIdx.x & 63;
    if (node >= N) return;
    int beg = rowptr[node], end = rowptr[node + 1];

    float d0 = 0.f, d1 = 0.f, d2 = 0.f;
    for (int jb = beg + lane; jb < end; jb += 64) {
        uint2 r = rec8[jb];
        d0 += __uint_as_float((r.x >> 1) & 0x7fff0000u);
        d1 += __uint_as_float((r.y << 16) & 0x7fff0000u);
        d2 += __uint_as_float((r.y << 1) & 0x7fff0000u);
    }
#pragma unroll
    for (int off = 32; off > 0; off >>= 1) {
        d0 += __shfl_xor(d0, off);
        d1 += __shfl_xor(d1, off);
        d2 += __shfl_xor(d2, off);
    }
    float inv0 = 1.f / (d0 + 1e-16f);
    float inv1 = 1.f / (d1 + 1e-16f);
    float inv2 = 1.f / (d2 + 1e-16f);

    float a0 = 0.f, a1 = 0.f;
    int j = beg;
    for (; j + 3 < end; j += 4) {
        uint2 r0 = rec8[j], r1 = rec8[j + 1], r2 = rec8[j + 2], r3 = rec8[j + 3];
        const uint32* p0 = Yu + (size_t)(r0.x & 0x1ffffu) * 192;
        const uint32* p1 = Yu + (size_t)(r1.x & 0x1ffffu) * 192;
        const uint32* p2 = Yu + (size_t)(r2.x & 0x1ffffu) * 192;
        const uint32* p3 = Yu + (size_t)(r3.x & 0x1ffffu) * 192;
        uint32 u00 = p0[lane], u01 = p0[64 + lane], u02 = p0[128 + lane];
        uint32 u10 = p1[lane], u11 = p1[64 + lane], u12 = p1[128 + lane];
        uint32 u20 = p2[lane], u21 = p2[64 + lane], u22 = p2[128 + lane];
        uint32 u30 = p3[lane], u31 = p3[64 + lane], u32 = p3[128 + lane];
        float w00 = __uint_as_float((r0.x >> 1) & 0x7fff0000u) * inv0;
        float w01 = __uint_as_float((r0.y << 16) & 0x7fff0000u) * inv1;
        float w02 = __uint_as_float((r0.y << 1) & 0x7fff0000u) * inv2;
        float w10 = __uint_as_float((r1.x >> 1) & 0x7fff0000u) * inv0;
        float w11 = __uint_as_float((r1.y << 16) & 0x7fff0000u) * inv1;
        float w12 = __uint_as_float((r1.y << 1) & 0x7fff0000u) * inv2;
        float w20 = __uint_as_float((r2.x >> 1) & 0x7fff0000u) * inv0;
        float w21 = __uint_as_float((r2.y << 16) & 0x7fff0000u) * inv1;
        float w22 = __uint_as_float((r2.y << 1) & 0x7fff0000u) * inv2;
        float w30 = __uint_as_float((r3.x >> 1) & 0x7fff0000u) * inv0;
        float w31 = __uint_as_float((r3.y << 16) & 0x7fff0000u) * inv1;
        float w32 = __uint_as_float((r3.y << 1) & 0x7fff0000u) * inv2;
        a0 += w00 * bflo(u00) + w01 * bflo(u01) + w02 * bflo(u02);
        a1 += w00 * bfhi(u00) + w01 * bfhi(u01) + w02 * bfhi(u02);
        a0 += w10 * bflo(u10) + w11 * bflo(u11) + w12 * bflo(u12);
        a1 += w10 * bfhi(u10) + w11 * bfhi(u11) + w12 * bfhi(u12);
        a0 += w20 * bflo(u20) + w21 * bflo(u21) + w22 * bflo(u22);
        a1 += w20 * bfhi(u20) + w21 * bfhi(u21) + w22 * bfhi(u22);
        a0 += w30 * bflo(u30) + w31 * bflo(u31) + w32 * bflo(u32);
        a1 += w30 * bfhi(u30) + w31 * bfhi(u31) + w32 * bfhi(u32);
    }
    for (; j < end; ++j) {
        uint2 r0 = rec8[j];
        const uint32* p0 = Yu + (size_t)(r0.x & 0x1ffffu) * 192;
        uint32 u00 = p0[lane], u01 = p0[64 + lane], u02 = p0[128 + lane];
        float w00 = __uint_as_float((r0.x >> 1) & 0x7fff0000u) * inv0;
        float w01 = __uint_as_float((r0.y << 16) & 0x7fff0000u) * inv1;
        float w02 = __uint_as_float((r0.y << 1) & 0x7fff0000u) * inv2;
        a0 += w00 * bflo(u00) + w01 * bflo(u01) + w02 * bflo(u02);
        a1 += w00 * bfhi(u00) + w01 * bfhi(u01) + w02 * bfhi(u02);
    }
    ((float2*)(out + (size_t)node * 128))[lane] = make_float2(a0, a1);
}

// ---------------------------------------------------------------------------
extern "C" void kernel_launch(void* const* d_in, const int* in_sizes, int n_in,
                              void* d_out, int out_size, void* d_ws, size_t ws_size,
                              hipStream_t stream) {
    const float* h    = (const float*)d_in[0];
    const int*   ei   = (const int*)d_in[1];    // [2, E]
    const float* ef   = (const float*)d_in[2];  // [E, 3]
    const float* W    = (const float*)d_in[3];  // [128,128]
    const float* a1   = (const float*)d_in[4];  // [128]
    const float* a2   = (const float*)d_in[5];  // [128]
    const float* Wout = (const float*)d_in[6];  // [384,128]
    float*       out  = (float*)d_out;

    const int N = in_sizes[0] / 128;  // 50000
    const int E = in_sizes[2] / 3;    // 800000
    const int nchunk = (N + 1023) / 1024;
    const int nbh    = (E + 255) / 256;   // hist blocks
    const int nbm    = (N + 63) / 64;     // mmy blocks

    // workspace layout (rec8 first -> 16B alignment for everything vectorized)
    uint2* rec8 = (uint2*)d_ws;                         // E * 8B
    unsigned short* Yb  = (unsigned short*)(rec8 + E);  // N*384 bf16
    unsigned short* WT2 = Yb + (size_t)N * 384;         // 3*128*128 bf16
    float* w1f  = (float*)(WT2 + 3 * 128 * 128);        // 128
    float* w2f  = w1f + 128;                            // 128
    float* s1   = w2f + 128;                            // N
    float* s2   = s1 + N;                               // N
    int* counts = (int*)(s2 + N);                       // N
    int* rowptr = counts + N;                           // N+1
    int* eslot  = rowptr + N + 1;                       // E

    (void)hipMemsetAsync(counts, 0, (size_t)N * sizeof(int), stream);

    k1_hist_prep<<<nbh + 25, 256, 0, stream>>>(ei, counts, eslot, E,
                                               W, Wout, a1, a2, WT2, w1f, w2f, nbh);
    k2_mmy_scan<<<nbm + nchunk, 256, 0, stream>>>(h, WT2, w1f, w2f, Yb, s1, s2, N,
                                                  counts, rowptr, N, E, nbm);
    scatter_kernel<<<(E + 255) / 256, 256, 0, stream>>>(ei, ef, s1, s2, rowptr, eslot, rec8, E);
    agg_kernel<<<(N * 64 + 255) / 256, 256, 0, stream>>>(rec8, rowptr, (const uint32*)Yb, out, N);
}